// Round 10
// baseline (188.150 us; speedup 1.0000x reference)
//
#include <hip/hip_runtime.h>
#include <hip/hip_bf16.h>

#define NN 8192
#define XDLEN 16448      // duplicated window length (covers i0 + j + 63)

typedef short bfrag8 __attribute__((ext_vector_type(8)));   // 8 bf16
typedef float floatx4 __attribute__((ext_vector_type(4)));
typedef float f4u __attribute__((ext_vector_type(4), aligned(4)));  // 4B-aligned float4

static __device__ __forceinline__ unsigned short f2bf(float f) {
  unsigned u = __builtin_bit_cast(unsigned, f);
  u = (u + 0x7FFFu + ((u >> 16) & 1u)) >> 16;   // RNE
  return (unsigned short)u;
}
static __device__ __forceinline__ unsigned cvt_pk_bf16(float a, float b) {
  return (unsigned)f2bf(a) | ((unsigned)f2bf(b) << 16);
}
static __device__ __forceinline__ unsigned trunc_pk_bf16(float a, float b) {
  unsigned ua = __builtin_bit_cast(unsigned, a);
  unsigned ub = __builtin_bit_cast(unsigned, b);
  return (ub & 0xFFFF0000u) | (ua >> 16);
}
static __device__ __forceinline__ float elu(float v) {
  return v > 0.f ? v : expm1f(v);
}

// ---- prep: W1 -> fragment-major bf16 W1F, W2^T bf16, xd (dup f32), regu ----
// W1F[((gq*4+n)*64 + l)*8 + e] = bf16(W1[(gq*32 + (l>>4)*8 + e)*64 + n*16 + (l&15)])
__global__ void prep_kernel(const float* __restrict__ x, const float* __restrict__ W1,
                            const float* __restrict__ W2, const float* __restrict__ rlen,
                            unsigned short* __restrict__ W1F, unsigned short* __restrict__ W2T,
                            float* __restrict__ xd, float* __restrict__ acc) {
  const int b = blockIdx.x, t = threadIdx.x;
  if (b < 128) {
    const int n = t >> 6, l = t & 63;
    const int lg = l >> 4, lr = l & 15;
#pragma unroll
    for (int qi = 0; qi < 2; ++qi) {
      const int gq = 2 * b + qi;
      unsigned short v[8];
#pragma unroll
      for (int e = 0; e < 8; ++e)
        v[e] = f2bf(W1[(gq * 32 + lg * 8 + e) * 64 + n * 16 + lr]);
      uint4 q;
      q.x = (unsigned)v[0] | ((unsigned)v[1] << 16);
      q.y = (unsigned)v[2] | ((unsigned)v[3] << 16);
      q.z = (unsigned)v[4] | ((unsigned)v[5] << 16);
      q.w = (unsigned)v[6] | ((unsigned)v[7] << 16);
      *(uint4*)(W1F + ((size_t)(gq * 4 + n) * 64 + l) * 8) = q;
    }
  } else if (b == 128) {
    for (int idx = t; idx < 64 * 64; idx += 256) {
      int k = idx >> 6, f = idx & 63;
      W2T[f * 64 + k] = f2bf(W2[idx]);
    }
  } else if (b < 132) {
    const int c = b - 129;
    for (int e = t * 4; e < XDLEN; e += 1024)
      *(float4*)&xd[c * XDLEN + e] = *(const float4*)&x[c * NN + (e & (NN - 1))];
  } else {
    float rl = rlen[0];
    float inv = 1.f / (2.f * rl * rl);
    int base = (b - 132) * 4096;
    float s1 = 0.f, s2 = 0.f;
    for (int ii = 0; ii < 16; ++ii) {
      int i = base + ii * 256 + t;
      float a0 = x[i], a1 = x[NN + i], a2 = x[2 * NN + i];
      float s = a0 * a0 + a1 * a1 + a2 * a2;
      s1 += s; s2 += expf(s * inv);
    }
    for (int d = 32; d > 0; d >>= 1) { s1 += __shfl_down(s1, d); s2 += __shfl_down(s2, d); }
    __shared__ float p1[4], p2[4];
    if ((t & 63) == 0) { p1[t >> 6] = s1; p2[t >> 6] = s2; }
    __syncthreads();
    if (t == 0) {
      atomicAdd(&acc[1], p1[0] + p1[1] + p1[2] + p1[3]);
      atomicAdd(&acc[2], p2[0] + p2[1] + p2[2] + p2[3]);
    }
  }
}

// ---- main: all-register corr fragments + MFMA; NO LDS/barriers in k-loop ---
// grid 1024 = 256 i-tiles x 4 k-quarters; 256 thr = 4 waves; wave owns chunks
// cq = ck*4+wv. A-frag lane(lg,lr): af[j] = sum_c xr[c] * xd[c][i0+k0+cb+row+lg*8+j]
// (global dwordx4, 4B-aligned legal). B-frag: coalesced uint4 from W1F.
__global__ __launch_bounds__(256, 2) void main_kernel(
    const float* __restrict__ x, const unsigned short* __restrict__ W1F,
    const float* __restrict__ xd, float* __restrict__ part) {
  __shared__ float h1[32 * 68];   // epilogue only (8.7 KB)

  const int t = threadIdx.x;
  const int ib = blockIdx.x >> 2, qb = blockIdx.x & 3;
  const int i0 = ib * 32, k0 = qb * 2048;
  const int wv = t >> 6, l = t & 63;
  const int lg = l >> 4, lr = l & 15;

  // per-lane row scalars (rows lr and 16+lr of this i-tile)
  float xr0[3], xr1[3];
#pragma unroll
  for (int c = 0; c < 3; ++c) {
    xr0[c] = x[c * NN + i0 + lr];
    xr1[c] = x[c * NN + i0 + 16 + lr];
  }

  // per-lane window base: xd[c] + i0 + k0 + lr + lg*8 (+cb per chunk)
  const float* wb = xd + i0 + k0 + lr + lg * 8;

  floatx4 acc[2][4];
#pragma unroll
  for (int m = 0; m < 2; ++m)
#pragma unroll
    for (int n = 0; n < 4; ++n)
      acc[m][n] = floatx4{0.f, 0.f, 0.f, 0.f};

  for (int ck = 0; ck < 16; ++ck) {
    const int cq = ck * 4 + wv;          // chunk within quarter (0..63)
    const int gq = qb * 64 + cq;         // global k-chunk
    // ---- B fragments: perfectly coalesced 1KB loads ----
    uint4 bv[4];
#pragma unroll
    for (int n = 0; n < 4; ++n)
      bv[n] = *(const uint4*)(W1F + ((size_t)(gq * 4 + n) * 64 + l) * 8);

    // ---- A fragments in registers: 12 dwordx4 + 48 FMA ----
    float af0[8], af1[8];
#pragma unroll
    for (int j = 0; j < 8; ++j) { af0[j] = 0.f; af1[j] = 0.f; }
#pragma unroll
    for (int c = 0; c < 3; ++c) {
      const float* p = wb + c * XDLEN + cq * 32;
      f4u u0 = *(const f4u*)(p);
      f4u u1 = *(const f4u*)(p + 4);
      f4u v0 = *(const f4u*)(p + 16);
      f4u v1 = *(const f4u*)(p + 20);
      const float a = xr0[c], bsc = xr1[c];
#pragma unroll
      for (int j = 0; j < 4; ++j) {
        af0[j]     = fmaf(a, u0[j], af0[j]);
        af0[4 + j] = fmaf(a, u1[j], af0[4 + j]);
        af1[j]     = fmaf(bsc, v0[j], af1[j]);
        af1[4 + j] = fmaf(bsc, v1[j], af1[4 + j]);
      }
    }
    uint4 qa = {trunc_pk_bf16(af0[0], af0[1]), trunc_pk_bf16(af0[2], af0[3]),
                trunc_pk_bf16(af0[4], af0[5]), trunc_pk_bf16(af0[6], af0[7])};
    uint4 qb2 = {trunc_pk_bf16(af1[0], af1[1]), trunc_pk_bf16(af1[2], af1[3]),
                 trunc_pk_bf16(af1[4], af1[5]), trunc_pk_bf16(af1[6], af1[7])};
    bfrag8 a0 = __builtin_bit_cast(bfrag8, qa);
    bfrag8 a1 = __builtin_bit_cast(bfrag8, qb2);
#pragma unroll
    for (int n = 0; n < 4; ++n) {
      bfrag8 bn = __builtin_bit_cast(bfrag8, bv[n]);
      acc[0][n] = __builtin_amdgcn_mfma_f32_16x16x32_bf16(a0, bn, acc[0][n], 0, 0, 0);
      acc[1][n] = __builtin_amdgcn_mfma_f32_16x16x32_bf16(a1, bn, acc[1][n], 0, 0, 0);
    }
  }

  // ---- epilogue: reduce 4 waves' partials, write quarter-part ----
  for (int q = t; q < 32 * 68; q += 256) h1[q] = 0.f;
  __syncthreads();
#pragma unroll
  for (int m = 0; m < 2; ++m)
#pragma unroll
    for (int n = 0; n < 4; ++n)
#pragma unroll
      for (int r = 0; r < 4; ++r)
        atomicAdd(&h1[(m * 16 + lg * 4 + r) * 68 + n * 16 + lr], acc[m][n][r]);
  __syncthreads();
  for (int q = t; q < 32 * 64; q += 256) {
    int row = q >> 6, col = q & 63;
    part[qb * (NN * 64) + (i0 + row) * 64 + col] = h1[row * 68 + col];
  }
}

// ---- tail: h1 = sum of 4 parts, elu -> @W2 -> elu -> @W3 -> row-sum -------
__global__ __launch_bounds__(256, 4) void tail_kernel(
    const float* __restrict__ part, const unsigned short* __restrict__ W2T,
    const float* __restrict__ W3, float* __restrict__ acc) {
  __shared__ float z3p[256];
  __shared__ float bsum[2];
  const int t = threadIdx.x;
  const int w4 = t >> 6, l = t & 63;
  const int lg = l >> 4, lr = l & 15;
  const int m2 = w4 & 1, np2 = w4 >> 1;
  const int i0 = blockIdx.x * 128;

  const float w3a = W3[np2 * 32 + lr];
  const float w3b = W3[np2 * 32 + 16 + lr];

#pragma unroll
  for (int rg = 0; rg < 4; ++rg) {
    const int rbase = i0 + rg * 32;
    floatx4 acc2_0 = {0.f, 0.f, 0.f, 0.f}, acc2_1 = {0.f, 0.f, 0.f, 0.f};
#pragma unroll
    for (int ks2 = 0; ks2 < 2; ++ks2) {
      const int kb = ks2 * 32 + lg * 8;
      const int row = rbase + m2 * 16 + lr;
      const float* p0 = &part[row * 64 + kb];
      const float* p1 = p0 + NN * 64;
      const float* p2 = p0 + 2 * NN * 64;
      const float* p3 = p0 + 3 * NN * 64;
      unsigned qa[4];
#pragma unroll
      for (int e = 0; e < 4; ++e) {
        float v0 = elu(p0[2 * e] + p1[2 * e] + p2[2 * e] + p3[2 * e]);
        float v1 = elu(p0[2 * e + 1] + p1[2 * e + 1] + p2[2 * e + 1] + p3[2 * e + 1]);
        qa[e] = cvt_pk_bf16(v0, v1);
      }
      uint4 qv = {qa[0], qa[1], qa[2], qa[3]};
      bfrag8 a2 = __builtin_bit_cast(bfrag8, qv);
#pragma unroll
      for (int tn = 0; tn < 2; ++tn) {
        int col2 = np2 * 32 + tn * 16 + lr;
        bfrag8 b2 = __builtin_bit_cast(bfrag8, *(const uint4*)&W2T[col2 * 64 + kb]);
        if (tn == 0)
          acc2_0 = __builtin_amdgcn_mfma_f32_16x16x32_bf16(a2, b2, acc2_0, 0, 0, 0);
        else
          acc2_1 = __builtin_amdgcn_mfma_f32_16x16x32_bf16(a2, b2, acc2_1, 0, 0, 0);
      }
    }
#pragma unroll
    for (int r = 0; r < 4; ++r) {
      float v = elu(acc2_0[r]) * w3a + elu(acc2_1[r]) * w3b;
      v += __shfl_xor(v, 1); v += __shfl_xor(v, 2);
      v += __shfl_xor(v, 4); v += __shfl_xor(v, 8);
      if (lr == 0)
        z3p[(rg * 32 + m2 * 16 + lg * 4 + r) * 2 + np2] = v;
    }
  }
  __syncthreads();
  if (t < 128) {
    float sv2 = z3p[t * 2] + z3p[t * 2 + 1];
    float z3 = elu(sv2);
    z3 += __shfl_xor(z3, 1); z3 += __shfl_xor(z3, 2); z3 += __shfl_xor(z3, 4);
    z3 += __shfl_xor(z3, 8); z3 += __shfl_xor(z3, 16); z3 += __shfl_xor(z3, 32);
    if ((t & 63) == 0) bsum[t >> 6] = z3;
  }
  __syncthreads();
  if (t == 0) atomicAdd(&acc[0], bsum[0] + bsum[1]);
}

// ---------------- finalize ------------------------------------------------
__global__ void fin_kernel(const float* __restrict__ acc, const float* __restrict__ regu2,
                           const float* __restrict__ regu, float* __restrict__ out) {
  if (threadIdx.x == 0)
    out[0] = acc[0] * (1.f / (float)NN) - regu2[0] * acc[1] - regu[0] * acc[2];
}

extern "C" void kernel_launch(void* const* d_in, const int* in_sizes, int n_in,
                              void* d_out, int out_size, void* d_ws, size_t ws_size,
                              hipStream_t stream) {
  const float* x     = (const float*)d_in[0];
  const float* W1    = (const float*)d_in[1];
  const float* W2    = (const float*)d_in[2];
  const float* W3    = (const float*)d_in[3];
  const float* regu2 = (const float*)d_in[4];
  const float* regu  = (const float*)d_in[5];
  const float* rlen  = (const float*)d_in[6];

  char* ws = (char*)d_ws;
  float* acc            = (float*)ws;                       // [0]=z3 sum, [1]=x2, [2]=exp
  unsigned short* W1F   = (unsigned short*)(ws + 16);       // 1 MB fragment-major
  unsigned short* W2T   = (unsigned short*)(ws + 1048592);  // 8 KB
  float* xd             = (float*)(ws + 1056784);           // 3*16448 f32 = 197 KB
  float* part           = (float*)(ws + 1254400);           // 4*8192*64 f32 = 8 MB

  (void)hipMemsetAsync(acc, 0, 16, stream);
  prep_kernel<<<134, 256, 0, stream>>>(x, W1, W2, rlen, W1F, W2T, xd, acc);
  main_kernel<<<1024, 256, 0, stream>>>(x, W1F, xd, part);
  tail_kernel<<<64, 256, 0, stream>>>(part, W2T, W3, acc);
  fin_kernel<<<1, 64, 0, stream>>>(acc, regu2, regu, (float*)d_out);
}

// Round 12
// 169.710 us; speedup vs baseline: 1.1087x; 1.1087x over previous
//
#include <hip/hip_runtime.h>
#include <hip/hip_bf16.h>

#define NN 8192
#define XDLEN 16448      // duplicated window length (covers i0 + j + 63)

typedef short bfrag8 __attribute__((ext_vector_type(8)));   // 8 bf16
typedef float floatx4 __attribute__((ext_vector_type(4)));
typedef float f4u __attribute__((ext_vector_type(4), aligned(4)));  // 4B-aligned float4

static __device__ __forceinline__ unsigned short f2bf(float f) {
  unsigned u = __builtin_bit_cast(unsigned, f);
  u = (u + 0x7FFFu + ((u >> 16) & 1u)) >> 16;   // RNE
  return (unsigned short)u;
}
static __device__ __forceinline__ unsigned cvt_pk_bf16(float a, float b) {
  return (unsigned)f2bf(a) | ((unsigned)f2bf(b) << 16);
}
static __device__ __forceinline__ unsigned trunc_pk_bf16(float a, float b) {
  unsigned ua = __builtin_bit_cast(unsigned, a);
  unsigned ub = __builtin_bit_cast(unsigned, b);
  return (ub & 0xFFFF0000u) | (ua >> 16);
}
static __device__ __forceinline__ float elu(float v) {
  return v > 0.f ? v : expm1f(v);
}

// ---- prep: W1 -> fragment-major bf16 W1F, W2^T bf16, xd (dup f32), regu ----
__global__ void prep_kernel(const float* __restrict__ x, const float* __restrict__ W1,
                            const float* __restrict__ W2, const float* __restrict__ rlen,
                            unsigned short* __restrict__ W1F, unsigned short* __restrict__ W2T,
                            float* __restrict__ xd, float* __restrict__ acc) {
  const int b = blockIdx.x, t = threadIdx.x;
  if (b < 128) {
    const int n = t >> 6, l = t & 63;
    const int lg = l >> 4, lr = l & 15;
#pragma unroll
    for (int qi = 0; qi < 2; ++qi) {
      const int gq = 2 * b + qi;
      unsigned short v[8];
#pragma unroll
      for (int e = 0; e < 8; ++e)
        v[e] = f2bf(W1[(gq * 32 + lg * 8 + e) * 64 + n * 16 + lr]);
      uint4 q;
      q.x = (unsigned)v[0] | ((unsigned)v[1] << 16);
      q.y = (unsigned)v[2] | ((unsigned)v[3] << 16);
      q.z = (unsigned)v[4] | ((unsigned)v[5] << 16);
      q.w = (unsigned)v[6] | ((unsigned)v[7] << 16);
      *(uint4*)(W1F + ((size_t)(gq * 4 + n) * 64 + l) * 8) = q;
    }
  } else if (b == 128) {
    for (int idx = t; idx < 64 * 64; idx += 256) {
      int k = idx >> 6, f = idx & 63;
      W2T[f * 64 + k] = f2bf(W2[idx]);
    }
  } else if (b < 132) {
    const int c = b - 129;
    for (int e = t * 4; e < XDLEN; e += 1024)
      *(float4*)&xd[c * XDLEN + e] = *(const float4*)&x[c * NN + (e & (NN - 1))];
  } else {
    float rl = rlen[0];
    float inv = 1.f / (2.f * rl * rl);
    int base = (b - 132) * 4096;
    float s1 = 0.f, s2 = 0.f;
    for (int ii = 0; ii < 16; ++ii) {
      int i = base + ii * 256 + t;
      float a0 = x[i], a1 = x[NN + i], a2 = x[2 * NN + i];
      float s = a0 * a0 + a1 * a1 + a2 * a2;
      s1 += s; s2 += expf(s * inv);
    }
    for (int d = 32; d > 0; d >>= 1) { s1 += __shfl_down(s1, d); s2 += __shfl_down(s2, d); }
    __shared__ float p1[4], p2[4];
    if ((t & 63) == 0) { p1[t >> 6] = s1; p2[t >> 6] = s2; }
    __syncthreads();
    if (t == 0) {
      atomicAdd(&acc[1], p1[0] + p1[1] + p1[2] + p1[3]);
      atomicAdd(&acc[2], p2[0] + p2[1] + p2[2] + p2[3]);
    }
  }
}

// ---- main: register corr fragments + MFMA, explicit 1-deep load pipeline ---
// grid 1024 = 256 i-tiles x 4 k-quarters; 256 thr = 4 waves.
// Fully-unrolled 16-chunk loop, ping-pong stages: loads for chunk ck+1 are
// ISSUED before computing chunk ck (R6's proven prefetch pattern, extended to
// all 16 loads). Epilogue atomic-adds into global h1g (no part round-trip).
__global__ __launch_bounds__(256, 2) void main_kernel(
    const float* __restrict__ x, const unsigned short* __restrict__ W1F,
    const float* __restrict__ xd, float* __restrict__ h1g) {
  __shared__ float h1[32 * 68];   // epilogue only (8.7 KB)

  const int t = threadIdx.x;
  const int ib = blockIdx.x >> 2, qb = blockIdx.x & 3;
  const int i0 = ib * 32, k0 = qb * 2048;
  const int wv = t >> 6, l = t & 63;
  const int lg = l >> 4, lr = l & 15;

  // per-lane row scalars (rows lr and 16+lr of this i-tile)
  float xr0[3], xr1[3];
#pragma unroll
  for (int c = 0; c < 3; ++c) {
    xr0[c] = x[c * NN + i0 + lr];
    xr1[c] = x[c * NN + i0 + 16 + lr];
  }

  const float* wb = xd + i0 + k0 + lr + lg * 8;

  floatx4 acc[2][4];
#pragma unroll
  for (int m = 0; m < 2; ++m)
#pragma unroll
    for (int n = 0; n < 4; ++n)
      acc[m][n] = floatx4{0.f, 0.f, 0.f, 0.f};

  // ping-pong load stages (literal-indexed after full unroll -> registers)
  f4u ca[2][12];
  uint4 cb[2][4];

  auto loads = [&](int S, int ck) {
    const int cq = ck * 4 + wv;
    const int gq = qb * 64 + cq;
#pragma unroll
    for (int n = 0; n < 4; ++n)
      cb[S][n] = *(const uint4*)(W1F + ((size_t)(gq * 4 + n) * 64 + l) * 8);
#pragma unroll
    for (int c = 0; c < 3; ++c) {
      const float* p = wb + c * XDLEN + cq * 32;
      ca[S][c * 4 + 0] = *(const f4u*)(p);
      ca[S][c * 4 + 1] = *(const f4u*)(p + 4);
      ca[S][c * 4 + 2] = *(const f4u*)(p + 16);
      ca[S][c * 4 + 3] = *(const f4u*)(p + 20);
    }
  };

  auto compute = [&](int S) {
    float af0[8], af1[8];
#pragma unroll
    for (int j = 0; j < 8; ++j) { af0[j] = 0.f; af1[j] = 0.f; }
#pragma unroll
    for (int c = 0; c < 3; ++c) {
      const f4u u0 = ca[S][c * 4 + 0], u1 = ca[S][c * 4 + 1];
      const f4u v0 = ca[S][c * 4 + 2], v1 = ca[S][c * 4 + 3];
      const float a = xr0[c], bsc = xr1[c];
#pragma unroll
      for (int j = 0; j < 4; ++j) {
        af0[j]     = fmaf(a, u0[j], af0[j]);
        af0[4 + j] = fmaf(a, u1[j], af0[4 + j]);
        af1[j]     = fmaf(bsc, v0[j], af1[j]);
        af1[4 + j] = fmaf(bsc, v1[j], af1[4 + j]);
      }
    }
    uint4 qa = {trunc_pk_bf16(af0[0], af0[1]), trunc_pk_bf16(af0[2], af0[3]),
                trunc_pk_bf16(af0[4], af0[5]), trunc_pk_bf16(af0[6], af0[7])};
    uint4 qb2 = {trunc_pk_bf16(af1[0], af1[1]), trunc_pk_bf16(af1[2], af1[3]),
                 trunc_pk_bf16(af1[4], af1[5]), trunc_pk_bf16(af1[6], af1[7])};
    bfrag8 a0 = __builtin_bit_cast(bfrag8, qa);
    bfrag8 a1 = __builtin_bit_cast(bfrag8, qb2);
#pragma unroll
    for (int n = 0; n < 4; ++n) {
      bfrag8 bn = __builtin_bit_cast(bfrag8, cb[S][n]);
      acc[0][n] = __builtin_amdgcn_mfma_f32_16x16x32_bf16(a0, bn, acc[0][n], 0, 0, 0);
      acc[1][n] = __builtin_amdgcn_mfma_f32_16x16x32_bf16(a1, bn, acc[1][n], 0, 0, 0);
    }
  };

  loads(0, 0);
#pragma unroll
  for (int ck = 0; ck < 16; ++ck) {
    const int cur = ck & 1;
    if (ck + 1 < 16) loads(cur ^ 1, ck + 1);   // issue next chunk's loads FIRST
    compute(cur);                               // then consume current chunk
  }

  // ---- epilogue: LDS-reduce 4 waves' partials, atomic-add into global h1g --
  for (int q = t; q < 32 * 68; q += 256) h1[q] = 0.f;
  __syncthreads();
#pragma unroll
  for (int m = 0; m < 2; ++m)
#pragma unroll
    for (int n = 0; n < 4; ++n)
#pragma unroll
      for (int r = 0; r < 4; ++r)
        atomicAdd(&h1[(m * 16 + lg * 4 + r) * 68 + n * 16 + lr], acc[m][n][r]);
  __syncthreads();
  for (int q = t; q < 32 * 64; q += 256) {
    int row = q >> 6, col = q & 63;
    atomicAdd(&h1g[(i0 + row) * 64 + col], h1[row * 68 + col]);
  }
}

// ---- tail: elu(h1g) @ W2 -> elu -> @W3 -> elu -> row-sum ------------------
__global__ __launch_bounds__(256, 4) void tail_kernel(
    const float* __restrict__ h1g, const unsigned short* __restrict__ W2T,
    const float* __restrict__ W3, float* __restrict__ acc) {
  __shared__ float z3p[256];
  __shared__ float bsum[2];
  const int t = threadIdx.x;
  const int w4 = t >> 6, l = t & 63;
  const int lg = l >> 4, lr = l & 15;
  const int m2 = w4 & 1, np2 = w4 >> 1;
  const int i0 = blockIdx.x * 128;

  const float w3a = W3[np2 * 32 + lr];
  const float w3b = W3[np2 * 32 + 16 + lr];

#pragma unroll
  for (int rg = 0; rg < 4; ++rg) {
    const int rbase = i0 + rg * 32;
    floatx4 acc2_0 = {0.f, 0.f, 0.f, 0.f}, acc2_1 = {0.f, 0.f, 0.f, 0.f};
#pragma unroll
    for (int ks2 = 0; ks2 < 2; ++ks2) {
      const int kb = ks2 * 32 + lg * 8;
      const int row = rbase + m2 * 16 + lr;
      const float* p0 = &h1g[row * 64 + kb];
      unsigned qa[4];
#pragma unroll
      for (int e = 0; e < 4; ++e) {
        float v0 = elu(p0[2 * e]);
        float v1 = elu(p0[2 * e + 1]);
        qa[e] = cvt_pk_bf16(v0, v1);
      }
      uint4 qv = {qa[0], qa[1], qa[2], qa[3]};
      bfrag8 a2 = __builtin_bit_cast(bfrag8, qv);
#pragma unroll
      for (int tn = 0; tn < 2; ++tn) {
        int col2 = np2 * 32 + tn * 16 + lr;
        bfrag8 b2 = __builtin_bit_cast(bfrag8, *(const uint4*)&W2T[col2 * 64 + kb]);
        if (tn == 0)
          acc2_0 = __builtin_amdgcn_mfma_f32_16x16x32_bf16(a2, b2, acc2_0, 0, 0, 0);
        else
          acc2_1 = __builtin_amdgcn_mfma_f32_16x16x32_bf16(a2, b2, acc2_1, 0, 0, 0);
      }
    }
#pragma unroll
    for (int r = 0; r < 4; ++r) {
      float v = elu(acc2_0[r]) * w3a + elu(acc2_1[r]) * w3b;
      v += __shfl_xor(v, 1); v += __shfl_xor(v, 2);
      v += __shfl_xor(v, 4); v += __shfl_xor(v, 8);
      if (lr == 0)
        z3p[(rg * 32 + m2 * 16 + lg * 4 + r) * 2 + np2] = v;
    }
  }
  __syncthreads();
  if (t < 128) {
    float sv2 = z3p[t * 2] + z3p[t * 2 + 1];
    float z3 = elu(sv2);
    z3 += __shfl_xor(z3, 1); z3 += __shfl_xor(z3, 2); z3 += __shfl_xor(z3, 4);
    z3 += __shfl_xor(z3, 8); z3 += __shfl_xor(z3, 16); z3 += __shfl_xor(z3, 32);
    if ((t & 63) == 0) bsum[t >> 6] = z3;
  }
  __syncthreads();
  if (t == 0) atomicAdd(&acc[0], bsum[0] + bsum[1]);
}

// ---------------- finalize ------------------------------------------------
__global__ void fin_kernel(const float* __restrict__ acc, const float* __restrict__ regu2,
                           const float* __restrict__ regu, float* __restrict__ out) {
  if (threadIdx.x == 0)
    out[0] = acc[0] * (1.f / (float)NN) - regu2[0] * acc[1] - regu[0] * acc[2];
}

extern "C" void kernel_launch(void* const* d_in, const int* in_sizes, int n_in,
                              void* d_out, int out_size, void* d_ws, size_t ws_size,
                              hipStream_t stream) {
  const float* x     = (const float*)d_in[0];
  const float* W1    = (const float*)d_in[1];
  const float* W2    = (const float*)d_in[2];
  const float* W3    = (const float*)d_in[3];
  const float* regu2 = (const float*)d_in[4];
  const float* regu  = (const float*)d_in[5];
  const float* rlen  = (const float*)d_in[6];

  char* ws = (char*)d_ws;
  float* acc            = (float*)ws;                       // [0]=z3 sum, [1]=x2, [2]=exp
  unsigned short* W1F   = (unsigned short*)(ws + 16);       // 1 MB fragment-major
  unsigned short* W2T   = (unsigned short*)(ws + 1048592);  // 8 KB
  float* xd             = (float*)(ws + 1056784);           // 197 KB dup f32 x
  float* h1g            = (float*)(ws + 1254160);           // 8192*64 f32 = 2 MB

  (void)hipMemsetAsync(acc, 0, 16, stream);
  (void)hipMemsetAsync(h1g, 0, NN * 64 * sizeof(float), stream);
  prep_kernel<<<134, 256, 0, stream>>>(x, W1, W2, rlen, W1F, W2T, xd, acc);
  main_kernel<<<1024, 256, 0, stream>>>(x, W1F, xd, h1g);
  tail_kernel<<<64, 256, 0, stream>>>(h1g, W2T, W3, acc);
  fin_kernel<<<1, 64, 0, stream>>>(acc, regu2, regu, (float*)d_out);
}